// Round 5
// baseline (8300.307 us; speedup 1.0000x reference)
//
#include <hip/hip_runtime.h>
#include <cstdint>
#include <cstddef>

typedef __attribute__((ext_vector_type(8))) short short8;
typedef __attribute__((ext_vector_type(4))) float floatx4;

constexpr int kSeq = 512;
constexpr int kBatch = 256;
constexpr int kIn = 15;
constexpr int kH = 512;
constexpr int kG = 4 * kH;                    // 2048 gate cols, order i,f,g,o
constexpr size_t kShmemBytes = 131072;        // 128 fragment-sets * 1 KB

__device__ __forceinline__ unsigned short f2bf(float f) {
    union { float f; unsigned u; } v; v.f = f;
    unsigned u = v.u;
    return (unsigned short)((u + 0x7fffu + ((u >> 16) & 1u)) >> 16);
}

__device__ __forceinline__ float sigm(float x) { return 1.0f / (1.0f + __expf(-x)); }
__device__ __forceinline__ float tanh_(float x) { return 1.0f - 2.0f / (1.0f + __expf(2.0f * x)); }

__global__ void k_conv(const float* __restrict__ src, unsigned short* __restrict__ dst, int n) {
    int i = blockIdx.x * blockDim.x + threadIdx.x;
    if (i < n) dst[i] = f2bf(src[i]);
}

__global__ void k_conv_pad(const float* __restrict__ src, unsigned short* __restrict__ dst, int rows) {
    int i = blockIdx.x * blockDim.x + threadIdx.x;
    if (i >= rows * 32) return;
    int r = i >> 5, k = i & 31;
    dst[i] = (k < kIn) ? f2bf(src[r * kIn + k]) : (unsigned short)0;
}

// Persistent kernel: all 513 pipeline phases in one launch.
// group g = blockIdx&3 (64 batch rows each); role = blockIdx>>2:
// 0..31 layer-1 (16 hidden units each), 32..63 layer-2.
// Producers: write-through agent atomic stores (h never dirty in L2).
// Consumers: per-phase acquire fence (buffer_inv, no writeback) + NORMAL
// cached dwordx4 loads -> 32x read redundancy absorbed by per-XCD L2/L1.
__global__ __launch_bounds__(256) void k_persist(
    const unsigned short* __restrict__ whh1b,
    const unsigned short* __restrict__ wih1b,
    const unsigned short* __restrict__ wih2b,
    const unsigned short* __restrict__ whh2b,
    const unsigned short* __restrict__ xb,
    const float* __restrict__ bih1, const float* __restrict__ bhh1,
    const float* __restrict__ bih2, const float* __restrict__ bhh2,
    unsigned short* __restrict__ h1b0, unsigned short* __restrict__ h1b1,
    unsigned short* __restrict__ h2b0, unsigned short* __restrict__ h2b1,
    float* __restrict__ h2f,
    unsigned* __restrict__ ctr)
{
    extern __shared__ unsigned short lw[];
    const int bid = blockIdx.x;
    const int g = bid & 3;
    const int role = bid >> 2;
    const bool is2 = role >= 32;
    const int j0 = (role & 31) << 4;
    const int tid = (int)threadIdx.x;
    const int wave = tid >> 6;
    const int lane = tid & 63;
    const int lcol = lane & 15;
    const int quad = lane >> 4;
    const int m0 = (g << 6) + wave * 16;
    const int arow = m0 + lcol;
    const int koff = quad * 8;

    // ---- stage weight slices into LDS, fragment-linear layout ----
    // fragment f at lw[f*512 .. f*512+511]; lane slot = lane*8 elems (16 B).
    // slot (qd,u) holds W[gate*512 + j0 + u][k = kk*32 + qd*8 .. +7].
    if (!is2) {
        for (int i = tid; i < 4096; i += 256) {
            int ln = i >> 6, gg = ln >> 4, u = ln & 15;
            int c = i & 63, kk = c >> 2, qd = c & 3;
            *(short8*)&lw[((gg * 16 + kk) << 9) + ((qd * 16 + u) << 3)] =
                *(const short8*)&whh1b[(size_t)((gg << 9) + j0 + u) * kH + c * 8];
        }
        for (int i = tid; i < 256; i += 256) {
            int ln = i >> 2, gg = ln >> 4, u = ln & 15;
            int qd = i & 3;
            *(short8*)&lw[((64 + gg) << 9) + ((qd * 16 + u) << 3)] =
                *(const short8*)&wih1b[((gg << 9) + j0 + u) * 32 + qd * 8];
        }
    } else {
        for (int i = tid; i < 4096; i += 256) {
            int ln = i >> 6, gg = ln >> 4, u = ln & 15;
            int c = i & 63, kk = c >> 2, qd = c & 3;
            int dst = ((gg * 16 + kk) << 9) + ((qd * 16 + u) << 3);
            size_t src = (size_t)((gg << 9) + j0 + u) * kH + c * 8;
            *(short8*)&lw[dst] = *(const short8*)&wih2b[src];
            *(short8*)&lw[dst + (64 << 9)] = *(const short8*)&whh2b[src];
        }
    }
    float bsum[4];
#pragma unroll
    for (int gg = 0; gg < 4; ++gg) {
        int n = (gg << 9) + j0 + lcol;
        bsum[gg] = is2 ? (bih2[n] + bhh2[n]) : (bih1[n] + bhh1[n]);
    }
    __syncthreads();

    // c-state in registers: this block owns its (m,j) tile for all 512 steps
    float creg[4] = {0.f, 0.f, 0.f, 0.f};
    unsigned* myctr = ctr + g * 64;   // 256-B separated per-group counters

    for (int t = 0; t <= kSeq; ++t) {
        const bool active = is2 ? (t >= 1) : (t < kSeq);
        if (active) {
            const int s = is2 ? (t - 1) : t;
            floatx4 acc[4];
#pragma unroll
            for (int gg = 0; gg < 4; ++gg)
                acc[gg] = (floatx4){bsum[gg], bsum[gg], bsum[gg], bsum[gg]};

            if (!is2) {
                const unsigned short* hprev = (s & 1) ? h1b0 : h1b1;   // h1[s-1]
                const unsigned short* hp = hprev + (size_t)arow * kH + koff;
                short8 a[16];
#pragma unroll
                for (int kk = 0; kk < 16; ++kk) a[kk] = *(const short8*)(hp + kk * 32);
#pragma unroll
                for (int kk = 0; kk < 16; ++kk) {
#pragma unroll
                    for (int gg = 0; gg < 4; ++gg) {
                        short8 b = *(const short8*)&lw[((gg * 16 + kk) << 9) + (lane << 3)];
                        acc[gg] = __builtin_amdgcn_mfma_f32_16x16x32_bf16(a[kk], b, acc[gg], 0, 0, 0);
                    }
                }
                {   // x_t contribution (padded K=32; xb is kernel-boundary coherent)
                    short8 ax = *(const short8*)(xb + ((size_t)s * kBatch + arow) * 32 + koff);
#pragma unroll
                    for (int gg = 0; gg < 4; ++gg) {
                        short8 b = *(const short8*)&lw[((64 + gg) << 9) + (lane << 3)];
                        acc[gg] = __builtin_amdgcn_mfma_f32_16x16x32_bf16(ax, b, acc[gg], 0, 0, 0);
                    }
                }
            } else {
                const unsigned short* h1s = (s & 1) ? h1b1 : h1b0;     // h1[s]
                const unsigned short* h2p = (s & 1) ? h2b0 : h2b1;     // h2[s-1]
                const unsigned short* hp1 = h1s + (size_t)arow * kH + koff;
                const unsigned short* hp2 = h2p + (size_t)arow * kH + koff;
                short8 a[16];
#pragma unroll
                for (int kk = 0; kk < 16; ++kk) a[kk] = *(const short8*)(hp1 + kk * 32);
#pragma unroll
                for (int kk = 0; kk < 16; ++kk) {
#pragma unroll
                    for (int gg = 0; gg < 4; ++gg) {
                        short8 b = *(const short8*)&lw[((gg * 16 + kk) << 9) + (lane << 3)];
                        acc[gg] = __builtin_amdgcn_mfma_f32_16x16x32_bf16(a[kk], b, acc[gg], 0, 0, 0);
                    }
                }
#pragma unroll
                for (int kk = 0; kk < 16; ++kk) a[kk] = *(const short8*)(hp2 + kk * 32);
#pragma unroll
                for (int kk = 0; kk < 16; ++kk) {
#pragma unroll
                    for (int gg = 0; gg < 4; ++gg) {
                        short8 b = *(const short8*)&lw[((64 + gg * 16 + kk) << 9) + (lane << 3)];
                        acc[gg] = __builtin_amdgcn_mfma_f32_16x16x32_bf16(a[kk], b, acc[gg], 0, 0, 0);
                    }
                }
            }

            // epilogue: C/D row = m0 + quad*4 + r, col = j0 + lcol
            unsigned short* hw = !is2 ? ((s & 1) ? h1b1 : h1b0)
                                      : ((s & 1) ? h2b1 : h2b0);
            const int j = j0 + lcol;
#pragma unroll
            for (int r = 0; r < 4; ++r) {
                int m = m0 + quad * 4 + r;
                size_t off = (size_t)m * kH + j;
                float gi = acc[0][r], gf = acc[1][r], ggv = acc[2][r], go = acc[3][r];
                float cn = sigm(gf) * creg[r] + sigm(gi) * tanh_(ggv);
                float hn = sigm(go) * tanh_(cn);
                creg[r] = cn;
                __hip_atomic_store(&hw[off], f2bf(hn),
                                   __ATOMIC_RELAXED, __HIP_MEMORY_SCOPE_AGENT);  // write-through
                if (is2 && s == kSeq - 1) h2f[off] = hn;
            }
        }

        if (t < kSeq) {
            // drain my h-stores to the coherence point, then group barrier
            __builtin_amdgcn_s_waitcnt(0);   // vmcnt(0) lgkmcnt(0) expcnt(0)
            __syncthreads();                 // all waves' stores drained
            if (tid == 0) {
                __hip_atomic_fetch_add(myctr, 1u, __ATOMIC_RELAXED, __HIP_MEMORY_SCOPE_AGENT);
                const unsigned target = 64u * (unsigned)(t + 1);
                while (__hip_atomic_load(myctr, __ATOMIC_RELAXED, __HIP_MEMORY_SCOPE_AGENT) < target)
                    __builtin_amdgcn_s_sleep(2);
            }
            __syncthreads();
            // acquire: invalidate stale L1/L2 h lines (no writeback — nothing
            // agent-shared is ever dirty in L2). Next phase reads h with
            // normal cached loads; redundancy is absorbed by per-XCD L2.
            __builtin_amdgcn_fence(__ATOMIC_ACQUIRE, "agent");
        }
    }
}

__global__ __launch_bounds__(64) void k_head(
    const float* __restrict__ h2f, const float* __restrict__ fc1w,
    const float* __restrict__ fc1b, const float* __restrict__ fcw,
    const float* __restrict__ fcb, float* __restrict__ out)
{
    int m = blockIdx.x;
    int j = threadIdx.x;
    const float* hr = h2f + (size_t)m * kH;
    const float* wr = fc1w + (size_t)j * kH;
    float sacc = 0.f;
    for (int k = 0; k < kH; ++k) sacc += fmaxf(hr[k], 0.f) * wr[k];
    float rv = fmaxf(sacc + fc1b[j], 0.f) * fcw[j];
#pragma unroll
    for (int off = 32; off >= 1; off >>= 1) rv += __shfl_down(rv, off);
    if (j == 0) out[m] = 2.0f * (rv + fcb[0]);
}

extern "C" void kernel_launch(void* const* d_in, const int* in_sizes, int n_in,
                              void* d_out, int out_size, void* d_ws, size_t ws_size,
                              hipStream_t stream) {
    const float* x    = (const float*)d_in[0];
    const float* Wih1 = (const float*)d_in[1];
    const float* Whh1 = (const float*)d_in[2];
    const float* bih1 = (const float*)d_in[3];
    const float* bhh1 = (const float*)d_in[4];
    const float* Wih2 = (const float*)d_in[5];
    const float* Whh2 = (const float*)d_in[6];
    const float* bih2 = (const float*)d_in[7];
    const float* bhh2 = (const float*)d_in[8];
    const float* fc1w = (const float*)d_in[9];
    const float* fc1b = (const float*)d_in[10];
    const float* fcw  = (const float*)d_in[11];
    const float* fcb  = (const float*)d_in[12];
    float* out = (float*)d_out;

    char* p = (char*)d_ws;
    auto take = [&](size_t bytes) -> char* {
        char* r = p;
        p += (bytes + 255) & ~(size_t)255;
        return r;
    };
    unsigned short* whh1b = (unsigned short*)take((size_t)kG * kH * 2);
    unsigned short* wih2b = (unsigned short*)take((size_t)kG * kH * 2);
    unsigned short* whh2b = (unsigned short*)take((size_t)kG * kH * 2);
    unsigned short* wih1b = (unsigned short*)take((size_t)kG * 32 * 2);
    unsigned short* xb    = (unsigned short*)take((size_t)kSeq * kBatch * 32 * 2);
    char* state = p;
    unsigned short* h1b0 = (unsigned short*)take((size_t)kBatch * kH * 2);
    unsigned short* h1b1 = (unsigned short*)take((size_t)kBatch * kH * 2);
    unsigned short* h2b0 = (unsigned short*)take((size_t)kBatch * kH * 2);
    unsigned short* h2b1 = (unsigned short*)take((size_t)kBatch * kH * 2);
    size_t state_bytes = (size_t)((char*)h2b1 + (size_t)kBatch * kH * 2 - state);
    float* h2f = (float*)take((size_t)kBatch * kH * 4);
    unsigned* ctr = (unsigned*)take(4096);

    hipMemsetAsync(state, 0, state_bytes, stream);
    hipMemsetAsync(ctr, 0, 4096, stream);

    int n = kG * kH;
    k_conv<<<(n + 255) / 256, 256, 0, stream>>>(Whh1, whh1b, n);
    k_conv<<<(n + 255) / 256, 256, 0, stream>>>(Wih2, wih2b, n);
    k_conv<<<(n + 255) / 256, 256, 0, stream>>>(Whh2, whh2b, n);
    k_conv_pad<<<(kG * 32 + 255) / 256, 256, 0, stream>>>(Wih1, wih1b, kG);
    k_conv_pad<<<(kSeq * kBatch * 32 + 255) / 256, 256, 0, stream>>>(x, xb, kSeq * kBatch);

    hipFuncSetAttribute((const void*)k_persist,
                        hipFuncAttributeMaxDynamicSharedMemorySize, (int)kShmemBytes);
    void* args[] = {&whh1b, &wih1b, &wih2b, &whh2b, &xb,
                    (void*)&bih1, (void*)&bhh1, (void*)&bih2, (void*)&bhh2,
                    &h1b0, &h1b1, &h2b0, &h2b1, &h2f, &ctr};
    hipError_t e = hipLaunchCooperativeKernel((const void*)k_persist, dim3(256), dim3(256),
                                              args, (unsigned)kShmemBytes, stream);
    if (e != hipSuccess) {
        k_persist<<<256, 256, kShmemBytes, stream>>>(
            whh1b, wih1b, wih2b, whh2b, xb, bih1, bhh1, bih2, bhh2,
            h1b0, h1b1, h2b0, h2b1, h2f, ctr);
    }

    k_head<<<kBatch, 64, 0, stream>>>(h2f, fc1w, fc1b, fcw, fcb, out);
}

// Round 6
// 5117.456 us; speedup vs baseline: 1.6220x; 1.6220x over previous
//
#include <hip/hip_runtime.h>
#include <cstdint>
#include <cstddef>

typedef __attribute__((ext_vector_type(8))) short short8;
typedef __attribute__((ext_vector_type(4))) float floatx4;

constexpr int kSeq = 512;
constexpr int kBatch = 256;
constexpr int kIn = 15;
constexpr int kH = 512;
constexpr int kG = 4 * kH;                    // 2048 gate cols, order i,f,g,o
constexpr size_t kShmemBytes = 131072;        // 128 fragment-sets * 1 KB
constexpr size_t kHSlot = (size_t)kBatch * kH;  // elements per h slot

__device__ __forceinline__ unsigned short f2bf(float f) {
    union { float f; unsigned u; } v; v.f = f;
    unsigned u = v.u;
    return (unsigned short)((u + 0x7fffu + ((u >> 16) & 1u)) >> 16);
}

__device__ __forceinline__ float sigm(float x) { return 1.0f / (1.0f + __expf(-x)); }
__device__ __forceinline__ float tanh_(float x) { return 1.0f - 2.0f / (1.0f + __expf(2.0f * x)); }

// 16-byte chunk via two 8-byte relaxed agent-scope atomic loads (LLC-direct).
__device__ __forceinline__ short8 ald16(const unsigned short* p) {
    union { unsigned long long q[2]; short8 v; } c;
    c.q[0] = __hip_atomic_load((const unsigned long long*)p,
                               __ATOMIC_RELAXED, __HIP_MEMORY_SCOPE_AGENT);
    c.q[1] = __hip_atomic_load((const unsigned long long*)(p + 4),
                               __ATOMIC_RELAXED, __HIP_MEMORY_SCOPE_AGENT);
    return c.v;
}

// Wave-0 poll: lanes 0..31 each watch one flag (64 B apart). Register cache fc
// exploits monotonicity — a satisfied wait does zero memory ops.
__device__ __forceinline__ void waitf(const int* flags, int tgt, int lane, int& fc) {
    if (tgt <= 0) return;
    bool watch = (lane < 32);
    if (__all(!watch || fc >= tgt)) return;
    for (;;) {
        if (watch && fc < tgt)
            fc = __hip_atomic_load(flags + lane * 16,
                                   __ATOMIC_RELAXED, __HIP_MEMORY_SCOPE_AGENT);
        if (__all(!watch || fc >= tgt)) return;
        __builtin_amdgcn_s_sleep(1);
    }
}

__global__ void k_conv(const float* __restrict__ src, unsigned short* __restrict__ dst, int n) {
    int i = blockIdx.x * blockDim.x + threadIdx.x;
    if (i < n) dst[i] = f2bf(src[i]);
}

__global__ void k_conv_pad(const float* __restrict__ src, unsigned short* __restrict__ dst, int rows) {
    int i = blockIdx.x * blockDim.x + threadIdx.x;
    if (i >= rows * 32) return;
    int r = i >> 5, k = i & 31;
    dst[i] = (k < kIn) ? f2bf(src[r * kIn + k]) : (unsigned short)0;
}

// Persistent kernel. group g = blockIdx&3 (64 batch rows); role = blockIdx>>2:
// 0..31 layer-1, 32..63 layer-2 (16 hidden units each).
// h1: 4-slot ring (L1 may run up to 3 steps ahead); h2: 2-slot ring.
// Flag protocol (flags store completed-step+1, monotone):
//   L1 step s: wait f1>=s   -> read h1[s-1]; GEMMs; wait f2>=s-2 (slot-free) ->
//              store h1[s] in slot s&3; flag s+1.
//   L2 step u: wait f2>=u   -> read h2[u-1]; h2-GEMM; wait f1>=u+1 ->
//              read h1[u]; h1-GEMM; store h2[u] slot u&1; flag u+1.
__global__ __launch_bounds__(256) void k_persist(
    const unsigned short* __restrict__ whh1b,
    const unsigned short* __restrict__ wih1b,
    const unsigned short* __restrict__ wih2b,
    const unsigned short* __restrict__ whh2b,
    const unsigned short* __restrict__ xb,
    const float* __restrict__ bih1, const float* __restrict__ bhh1,
    const float* __restrict__ bih2, const float* __restrict__ bhh2,
    unsigned short* __restrict__ h1r,   // 4 slots of kBatch*kH
    unsigned short* __restrict__ h2r,   // 2 slots of kBatch*kH
    float* __restrict__ h2f,
    int* __restrict__ flags)            // per group: f1[32] @ +0, f2[32] @ +512 ints
{
    extern __shared__ unsigned short lw[];
    const int bid = blockIdx.x;
    const int g = bid & 3;
    const int role = bid >> 2;
    const bool is2 = role >= 32;
    const int rid = role & 31;
    const int j0 = rid << 4;
    const int tid = (int)threadIdx.x;
    const int wave = tid >> 6;
    const int lane = tid & 63;
    const int lcol = lane & 15;
    const int quad = lane >> 4;
    const int m0 = (g << 6) + wave * 16;
    const int arow = m0 + lcol;
    const int koff = quad * 8;

    int* f1 = flags + g * 1024;
    int* f2 = f1 + 512;
    int* myflag = (is2 ? f2 : f1) + rid * 16;

    // ---- stage weight slices into LDS, fragment-linear layout (as R4) ----
    if (!is2) {
        for (int i = tid; i < 4096; i += 256) {
            int ln = i >> 6, gg = ln >> 4, u = ln & 15;
            int c = i & 63, kk = c >> 2, qd = c & 3;
            *(short8*)&lw[((gg * 16 + kk) << 9) + ((qd * 16 + u) << 3)] =
                *(const short8*)&whh1b[(size_t)((gg << 9) + j0 + u) * kH + c * 8];
        }
        for (int i = tid; i < 256; i += 256) {
            int ln = i >> 2, gg = ln >> 4, u = ln & 15;
            int qd = i & 3;
            *(short8*)&lw[((64 + gg) << 9) + ((qd * 16 + u) << 3)] =
                *(const short8*)&wih1b[((gg << 9) + j0 + u) * 32 + qd * 8];
        }
    } else {
        for (int i = tid; i < 4096; i += 256) {
            int ln = i >> 6, gg = ln >> 4, u = ln & 15;
            int c = i & 63, kk = c >> 2, qd = c & 3;
            int dst = ((gg * 16 + kk) << 9) + ((qd * 16 + u) << 3);
            size_t src = (size_t)((gg << 9) + j0 + u) * kH + c * 8;
            *(short8*)&lw[dst] = *(const short8*)&wih2b[src];
            *(short8*)&lw[dst + (64 << 9)] = *(const short8*)&whh2b[src];
        }
    }
    float bsum[4];
#pragma unroll
    for (int gg = 0; gg < 4; ++gg) {
        int n = (gg << 9) + j0 + lcol;
        bsum[gg] = is2 ? (bih2[n] + bhh2[n]) : (bih1[n] + bhh1[n]);
    }
    __syncthreads();

    float creg[4] = {0.f, 0.f, 0.f, 0.f};
    int fc1 = 0, fc2 = 0;   // wave-0 flag caches

    if (!is2) {
        for (int s = 0; s < kSeq; ++s) {
            floatx4 acc[4];
#pragma unroll
            for (int gg = 0; gg < 4; ++gg)
                acc[gg] = (floatx4){bsum[gg], bsum[gg], bsum[gg], bsum[gg]};

            // x_t load (phase-independent input) issued before any wait
            short8 ax = *(const short8*)(xb + ((size_t)s * kBatch + arow) * 32 + koff);

            if (wave == 0) waitf(f1, s, lane, fc1);     // peers done s-1
            __syncthreads();

            const unsigned short* hp = h1r + ((size_t)((s + 3) & 3)) * kHSlot
                                       + (size_t)arow * kH + koff;   // h1[s-1]
            short8 a[16];
#pragma unroll
            for (int kk = 0; kk < 16; ++kk) a[kk] = ald16(hp + kk * 32);
#pragma unroll
            for (int kk = 0; kk < 16; ++kk) {
#pragma unroll
                for (int gg = 0; gg < 4; ++gg) {
                    short8 b = *(const short8*)&lw[((gg * 16 + kk) << 9) + (lane << 3)];
                    acc[gg] = __builtin_amdgcn_mfma_f32_16x16x32_bf16(a[kk], b, acc[gg], 0, 0, 0);
                }
            }
#pragma unroll
            for (int gg = 0; gg < 4; ++gg) {
                short8 b = *(const short8*)&lw[((64 + gg) << 9) + (lane << 3)];
                acc[gg] = __builtin_amdgcn_mfma_f32_16x16x32_bf16(ax, b, acc[gg], 0, 0, 0);
            }

            if (wave == 0) waitf(f2, s - 2, lane, fc2); // ring slot s&3 free
            __syncthreads();

            unsigned short* hw = h1r + ((size_t)(s & 3)) * kHSlot;
            const int j = j0 + lcol;
#pragma unroll
            for (int r = 0; r < 4; ++r) {
                int m = m0 + quad * 4 + r;
                size_t off = (size_t)m * kH + j;
                float gi = acc[0][r], gf = acc[1][r], ggv = acc[2][r], go = acc[3][r];
                float cn = sigm(gf) * creg[r] + sigm(gi) * tanh_(ggv);
                float hn = sigm(go) * tanh_(cn);
                creg[r] = cn;
                __hip_atomic_store(&hw[off], f2bf(hn),
                                   __ATOMIC_RELAXED, __HIP_MEMORY_SCOPE_AGENT);
            }
            __builtin_amdgcn_s_waitcnt(0);
            __syncthreads();
            if (tid == 0)
                __hip_atomic_store(myflag, s + 1,
                                   __ATOMIC_RELAXED, __HIP_MEMORY_SCOPE_AGENT);
        }
    } else {
        for (int u = 0; u < kSeq; ++u) {
            floatx4 acc[4];
#pragma unroll
            for (int gg = 0; gg < 4; ++gg)
                acc[gg] = (floatx4){bsum[gg], bsum[gg], bsum[gg], bsum[gg]};

            if (wave == 0) waitf(f2, u, lane, fc2);     // peers done u-1
            __syncthreads();

            // h2[u-1] GEMM first (hides under L1's tail)
            const unsigned short* hp2 = h2r + ((size_t)((u + 1) & 1)) * kHSlot
                                        + (size_t)arow * kH + koff;
            short8 a[16];
#pragma unroll
            for (int kk = 0; kk < 16; ++kk) a[kk] = ald16(hp2 + kk * 32);
#pragma unroll
            for (int kk = 0; kk < 16; ++kk) {
#pragma unroll
                for (int gg = 0; gg < 4; ++gg) {
                    short8 b = *(const short8*)&lw[((64 + gg * 16 + kk) << 9) + (lane << 3)];
                    acc[gg] = __builtin_amdgcn_mfma_f32_16x16x32_bf16(a[kk], b, acc[gg], 0, 0, 0);
                }
            }

            if (wave == 0) waitf(f1, u + 1, lane, fc1); // L1 done step u
            __syncthreads();

            const unsigned short* hp1 = h1r + ((size_t)(u & 3)) * kHSlot
                                        + (size_t)arow * kH + koff;   // h1[u]
#pragma unroll
            for (int kk = 0; kk < 16; ++kk) a[kk] = ald16(hp1 + kk * 32);
#pragma unroll
            for (int kk = 0; kk < 16; ++kk) {
#pragma unroll
                for (int gg = 0; gg < 4; ++gg) {
                    short8 b = *(const short8*)&lw[((gg * 16 + kk) << 9) + (lane << 3)];
                    acc[gg] = __builtin_amdgcn_mfma_f32_16x16x32_bf16(a[kk], b, acc[gg], 0, 0, 0);
                }
            }

            unsigned short* hw = h2r + ((size_t)(u & 1)) * kHSlot;
            const int j = j0 + lcol;
#pragma unroll
            for (int r = 0; r < 4; ++r) {
                int m = m0 + quad * 4 + r;
                size_t off = (size_t)m * kH + j;
                float gi = acc[0][r], gf = acc[1][r], ggv = acc[2][r], go = acc[3][r];
                float cn = sigm(gf) * creg[r] + sigm(gi) * tanh_(ggv);
                float hn = sigm(go) * tanh_(cn);
                creg[r] = cn;
                __hip_atomic_store(&hw[off], f2bf(hn),
                                   __ATOMIC_RELAXED, __HIP_MEMORY_SCOPE_AGENT);
                if (u == kSeq - 1) h2f[off] = hn;
            }
            __builtin_amdgcn_s_waitcnt(0);
            __syncthreads();
            if (tid == 0)
                __hip_atomic_store(myflag, u + 1,
                                   __ATOMIC_RELAXED, __HIP_MEMORY_SCOPE_AGENT);
        }
    }
}

__global__ __launch_bounds__(64) void k_head(
    const float* __restrict__ h2f, const float* __restrict__ fc1w,
    const float* __restrict__ fc1b, const float* __restrict__ fcw,
    const float* __restrict__ fcb, float* __restrict__ out)
{
    int m = blockIdx.x;
    int j = threadIdx.x;
    const float* hr = h2f + (size_t)m * kH;
    const float* wr = fc1w + (size_t)j * kH;
    float sacc = 0.f;
    for (int k = 0; k < kH; ++k) sacc += fmaxf(hr[k], 0.f) * wr[k];
    float rv = fmaxf(sacc + fc1b[j], 0.f) * fcw[j];
#pragma unroll
    for (int off = 32; off >= 1; off >>= 1) rv += __shfl_down(rv, off);
    if (j == 0) out[m] = 2.0f * (rv + fcb[0]);
}

extern "C" void kernel_launch(void* const* d_in, const int* in_sizes, int n_in,
                              void* d_out, int out_size, void* d_ws, size_t ws_size,
                              hipStream_t stream) {
    const float* x    = (const float*)d_in[0];
    const float* Wih1 = (const float*)d_in[1];
    const float* Whh1 = (const float*)d_in[2];
    const float* bih1 = (const float*)d_in[3];
    const float* bhh1 = (const float*)d_in[4];
    const float* Wih2 = (const float*)d_in[5];
    const float* Whh2 = (const float*)d_in[6];
    const float* bih2 = (const float*)d_in[7];
    const float* bhh2 = (const float*)d_in[8];
    const float* fc1w = (const float*)d_in[9];
    const float* fc1b = (const float*)d_in[10];
    const float* fcw  = (const float*)d_in[11];
    const float* fcb  = (const float*)d_in[12];
    float* out = (float*)d_out;

    char* p = (char*)d_ws;
    auto take = [&](size_t bytes) -> char* {
        char* r = p;
        p += (bytes + 255) & ~(size_t)255;
        return r;
    };
    unsigned short* whh1b = (unsigned short*)take((size_t)kG * kH * 2);
    unsigned short* wih2b = (unsigned short*)take((size_t)kG * kH * 2);
    unsigned short* whh2b = (unsigned short*)take((size_t)kG * kH * 2);
    unsigned short* wih1b = (unsigned short*)take((size_t)kG * 32 * 2);
    unsigned short* xb    = (unsigned short*)take((size_t)kSeq * kBatch * 32 * 2);
    char* state = p;
    unsigned short* h1r = (unsigned short*)take(4 * kHSlot * 2);
    unsigned short* h2r = (unsigned short*)take(2 * kHSlot * 2);
    int* flags = (int*)take(16384);
    size_t state_bytes = (size_t)((char*)flags + 16384 - state);
    float* h2f = (float*)take((size_t)kBatch * kH * 4);

    hipMemsetAsync(state, 0, state_bytes, stream);

    int n = kG * kH;
    k_conv<<<(n + 255) / 256, 256, 0, stream>>>(Whh1, whh1b, n);
    k_conv<<<(n + 255) / 256, 256, 0, stream>>>(Wih2, wih2b, n);
    k_conv<<<(n + 255) / 256, 256, 0, stream>>>(Whh2, whh2b, n);
    k_conv_pad<<<(kG * 32 + 255) / 256, 256, 0, stream>>>(Wih1, wih1b, kG);
    k_conv_pad<<<(kSeq * kBatch * 32 + 255) / 256, 256, 0, stream>>>(x, xb, kSeq * kBatch);

    hipFuncSetAttribute((const void*)k_persist,
                        hipFuncAttributeMaxDynamicSharedMemorySize, (int)kShmemBytes);
    void* args[] = {&whh1b, &wih1b, &wih2b, &whh2b, &xb,
                    (void*)&bih1, (void*)&bhh1, (void*)&bih2, (void*)&bhh2,
                    &h1r, &h2r, &h2f, &flags};
    hipError_t e = hipLaunchCooperativeKernel((const void*)k_persist, dim3(256), dim3(256),
                                              args, (unsigned)kShmemBytes, stream);
    if (e != hipSuccess) {
        k_persist<<<256, 256, kShmemBytes, stream>>>(
            whh1b, wih1b, wih2b, whh2b, xb, bih1, bhh1, bih2, bhh2,
            h1r, h2r, h2f, flags);
    }

    k_head<<<kBatch, 64, 0, stream>>>(h2f, fc1w, fc1b, fcw, fcb, out);
}

// Round 7
// 4257.902 us; speedup vs baseline: 1.9494x; 1.2019x over previous
//
#include <hip/hip_runtime.h>
#include <cstdint>
#include <cstddef>

typedef __attribute__((ext_vector_type(8))) short short8;
typedef __attribute__((ext_vector_type(4))) float floatx4;

constexpr int kSeq = 512;
constexpr int kBatch = 256;
constexpr int kIn = 15;
constexpr int kH = 512;
constexpr int kG = 4 * kH;                      // 2048 gate cols, order i,f,g,o
constexpr size_t kHSlot = (size_t)kBatch * kH;  // elements per h slot
// LDS: 128 KB weights (fragment-linear) + 4 waves * 768 B transpose scratch
constexpr size_t kShmemBytes = 131072 + 4096;

__device__ __forceinline__ unsigned short f2bf(float f) {
    union { float f; unsigned u; } v; v.f = f;
    unsigned u = v.u;
    return (unsigned short)((u + 0x7fffu + ((u >> 16) & 1u)) >> 16);
}

__device__ __forceinline__ float sigm(float x) { return 1.0f / (1.0f + __expf(-x)); }
__device__ __forceinline__ float tanh_(float x) { return 1.0f - 2.0f / (1.0f + __expf(2.0f * x)); }

// 16 LLC-direct 16-B loads (64 B apart) + ONE trailing waitcnt, all in a single
// asm block. Outputs are EARLY-CLOBBER ("=&v") so no output tuple can overlay
// the address register (the suspected R3 hang).
#define LLC_LOAD16(A, P)                                                      \
    asm volatile(                                                             \
        "global_load_dwordx4 %0, %16, off sc0 sc1\n\t"                        \
        "global_load_dwordx4 %1, %16, off offset:64 sc0 sc1\n\t"              \
        "global_load_dwordx4 %2, %16, off offset:128 sc0 sc1\n\t"             \
        "global_load_dwordx4 %3, %16, off offset:192 sc0 sc1\n\t"             \
        "global_load_dwordx4 %4, %16, off offset:256 sc0 sc1\n\t"             \
        "global_load_dwordx4 %5, %16, off offset:320 sc0 sc1\n\t"             \
        "global_load_dwordx4 %6, %16, off offset:384 sc0 sc1\n\t"             \
        "global_load_dwordx4 %7, %16, off offset:448 sc0 sc1\n\t"             \
        "global_load_dwordx4 %8, %16, off offset:512 sc0 sc1\n\t"             \
        "global_load_dwordx4 %9, %16, off offset:576 sc0 sc1\n\t"             \
        "global_load_dwordx4 %10, %16, off offset:640 sc0 sc1\n\t"            \
        "global_load_dwordx4 %11, %16, off offset:704 sc0 sc1\n\t"            \
        "global_load_dwordx4 %12, %16, off offset:768 sc0 sc1\n\t"            \
        "global_load_dwordx4 %13, %16, off offset:832 sc0 sc1\n\t"            \
        "global_load_dwordx4 %14, %16, off offset:896 sc0 sc1\n\t"            \
        "global_load_dwordx4 %15, %16, off offset:960 sc0 sc1\n\t"            \
        "s_waitcnt vmcnt(0)"                                                  \
        : "=&v"((A)[0]), "=&v"((A)[1]), "=&v"((A)[2]), "=&v"((A)[3]),         \
          "=&v"((A)[4]), "=&v"((A)[5]), "=&v"((A)[6]), "=&v"((A)[7]),         \
          "=&v"((A)[8]), "=&v"((A)[9]), "=&v"((A)[10]), "=&v"((A)[11]),       \
          "=&v"((A)[12]), "=&v"((A)[13]), "=&v"((A)[14]), "=&v"((A)[15])      \
        : "v"(P) : "memory")

// 16-B LLC-direct store (write-through; no outputs -> no clobber hazard)
#define LLC_STORE16(P, V)                                                     \
    asm volatile("global_store_dwordx4 %0, %1, off sc0 sc1"                   \
                 :: "v"(P), "v"(V) : "memory")

// Wave-0 poll: lanes 0..31 each watch one flag (64 B apart). Register cache fc
// exploits monotonicity — a satisfied wait does zero memory ops.
__device__ __forceinline__ void waitf(const int* flags, int tgt, int lane, int& fc) {
    if (tgt <= 0) return;
    bool watch = (lane < 32);
    if (__all(!watch || fc >= tgt)) return;
    for (;;) {
        if (watch && fc < tgt)
            fc = __hip_atomic_load(flags + lane * 16,
                                   __ATOMIC_RELAXED, __HIP_MEMORY_SCOPE_AGENT);
        if (__all(!watch || fc >= tgt)) return;
        __builtin_amdgcn_s_sleep(1);
    }
}

__global__ void k_conv(const float* __restrict__ src, unsigned short* __restrict__ dst, int n) {
    int i = blockIdx.x * blockDim.x + threadIdx.x;
    if (i < n) dst[i] = f2bf(src[i]);
}

__global__ void k_conv_pad(const float* __restrict__ src, unsigned short* __restrict__ dst, int rows) {
    int i = blockIdx.x * blockDim.x + threadIdx.x;
    if (i >= rows * 32) return;
    int r = i >> 5, k = i & 31;
    dst[i] = (k < kIn) ? f2bf(src[r * kIn + k]) : (unsigned short)0;
}

// Persistent kernel. group g = blockIdx&3 (64 batch rows); role = blockIdx>>2:
// 0..31 layer-1, 32..63 layer-2 (16 hidden units each).
// h1: 4-slot ring (L1 up to 3 steps ahead); h2: 2-slot ring.
// Flag protocol (flags = completed-step+1, monotone):
//   L1 step s: wait f1>=s -> read h1[s-1]; GEMMs; wait f2>=s-2 (slot free) ->
//              store h1[s] slot s&3; flag s+1.
//   L2 step u: wait f2>=u -> read h2[u-1]; h2-GEMM; wait f1>=u+1 ->
//              read h1[u]; h1-GEMM; store h2[u] slot u&1; flag u+1.
__global__ __launch_bounds__(256) void k_persist(
    const unsigned short* __restrict__ whh1b,
    const unsigned short* __restrict__ wih1b,
    const unsigned short* __restrict__ wih2b,
    const unsigned short* __restrict__ whh2b,
    const unsigned short* __restrict__ xb,
    const float* __restrict__ bih1, const float* __restrict__ bhh1,
    const float* __restrict__ bih2, const float* __restrict__ bhh2,
    unsigned short* __restrict__ h1r,   // 4 slots of kBatch*kH
    unsigned short* __restrict__ h2r,   // 2 slots of kBatch*kH
    float* __restrict__ h2f,
    int* __restrict__ flags)            // per group: f1[32] @ +0, f2[32] @ +512 ints
{
    extern __shared__ unsigned short lw[];
    const int bid = blockIdx.x;
    const int g = bid & 3;
    const int role = bid >> 2;
    const bool is2 = role >= 32;
    const int rid = role & 31;
    const int j0 = rid << 4;
    const int tid = (int)threadIdx.x;
    const int wave = tid >> 6;
    const int lane = tid & 63;
    const int lcol = lane & 15;
    const int quad = lane >> 4;
    const int m0 = (g << 6) + wave * 16;
    const int arow = m0 + lcol;
    const int koff = quad * 8;

    int* f1 = flags + g * 1024;
    int* f2 = f1 + 512;
    int* myflag = (is2 ? f2 : f1) + rid * 16;
    unsigned short* scr = lw + 65536 + wave * 384;   // 16 rows x stride-24 elems

    // ---- stage weight slices into LDS, fragment-linear layout ----
    if (!is2) {
        for (int i = tid; i < 4096; i += 256) {
            int ln = i >> 6, gg = ln >> 4, u = ln & 15;
            int c = i & 63, kk = c >> 2, qd = c & 3;
            *(short8*)&lw[((gg * 16 + kk) << 9) + ((qd * 16 + u) << 3)] =
                *(const short8*)&whh1b[(size_t)((gg << 9) + j0 + u) * kH + c * 8];
        }
        for (int i = tid; i < 256; i += 256) {
            int ln = i >> 2, gg = ln >> 4, u = ln & 15;
            int qd = i & 3;
            *(short8*)&lw[((64 + gg) << 9) + ((qd * 16 + u) << 3)] =
                *(const short8*)&wih1b[((gg << 9) + j0 + u) * 32 + qd * 8];
        }
    } else {
        for (int i = tid; i < 4096; i += 256) {
            int ln = i >> 6, gg = ln >> 4, u = ln & 15;
            int c = i & 63, kk = c >> 2, qd = c & 3;
            int dst = ((gg * 16 + kk) << 9) + ((qd * 16 + u) << 3);
            size_t src = (size_t)((gg << 9) + j0 + u) * kH + c * 8;
            *(short8*)&lw[dst] = *(const short8*)&wih2b[src];
            *(short8*)&lw[dst + (64 << 9)] = *(const short8*)&whh2b[src];
        }
    }
    float bsum[4];
#pragma unroll
    for (int gg = 0; gg < 4; ++gg) {
        int n = (gg << 9) + j0 + lcol;
        bsum[gg] = is2 ? (bih2[n] + bhh2[n]) : (bih1[n] + bhh1[n]);
    }
    __syncthreads();

    float creg[4] = {0.f, 0.f, 0.f, 0.f};
    int fc1 = 0, fc2 = 0;   // wave-0 flag caches

    if (!is2) {
        for (int s = 0; s < kSeq; ++s) {
            floatx4 acc[4];
#pragma unroll
            for (int gg = 0; gg < 4; ++gg)
                acc[gg] = (floatx4){bsum[gg], bsum[gg], bsum[gg], bsum[gg]};

            // x_t load (phase-independent input) issued before any wait
            short8 ax = *(const short8*)(xb + ((size_t)s * kBatch + arow) * 32 + koff);

            if (wave == 0) waitf(f1, s, lane, fc1);     // peers done s-1
            __syncthreads();

            const unsigned short* hp = h1r + ((size_t)((s + 3) & 3)) * kHSlot
                                       + (size_t)arow * kH + koff;   // h1[s-1]
            short8 a[16];
            LLC_LOAD16(a, hp);
#pragma unroll
            for (int kk = 0; kk < 16; ++kk) {
#pragma unroll
                for (int gg = 0; gg < 4; ++gg) {
                    short8 b = *(const short8*)&lw[((gg * 16 + kk) << 9) + (lane << 3)];
                    acc[gg] = __builtin_amdgcn_mfma_f32_16x16x32_bf16(a[kk], b, acc[gg], 0, 0, 0);
                }
            }
#pragma unroll
            for (int gg = 0; gg < 4; ++gg) {
                short8 b = *(const short8*)&lw[((64 + gg) << 9) + (lane << 3)];
                acc[gg] = __builtin_amdgcn_mfma_f32_16x16x32_bf16(ax, b, acc[gg], 0, 0, 0);
            }

            if (wave == 0) waitf(f2, s - 2, lane, fc2); // ring slot s&3 free
            __syncthreads();

            // epilogue: activations -> per-wave LDS transpose -> 16B LLC stores
            unsigned short* hw = h1r + ((size_t)(s & 3)) * kHSlot;
#pragma unroll
            for (int r = 0; r < 4; ++r) {
                int row = quad * 4 + r;
                float gi = acc[0][r], gf = acc[1][r], ggv = acc[2][r], go = acc[3][r];
                float cn = sigm(gf) * creg[r] + sigm(gi) * tanh_(ggv);
                float hn = sigm(go) * tanh_(cn);
                creg[r] = cn;
                scr[row * 24 + lcol] = f2bf(hn);
            }
            __syncthreads();
            if (lane < 32) {
                int row = lane >> 1, seg = lane & 1;
                short8 v = *(short8*)&scr[row * 24 + seg * 8];
                unsigned short* gp = hw + (size_t)(m0 + row) * kH + j0 + seg * 8;
                LLC_STORE16(gp, v);
            }
            __builtin_amdgcn_s_waitcnt(0);
            __syncthreads();
            if (tid == 0)
                __hip_atomic_store(myflag, s + 1,
                                   __ATOMIC_RELAXED, __HIP_MEMORY_SCOPE_AGENT);
        }
    } else {
        for (int u = 0; u < kSeq; ++u) {
            floatx4 acc[4];
#pragma unroll
            for (int gg = 0; gg < 4; ++gg)
                acc[gg] = (floatx4){bsum[gg], bsum[gg], bsum[gg], bsum[gg]};

            if (wave == 0) waitf(f2, u, lane, fc2);     // peers done u-1
            __syncthreads();

            // h2[u-1] GEMM first (hides under L1's tail)
            const unsigned short* hp2 = h2r + ((size_t)((u + 1) & 1)) * kHSlot
                                        + (size_t)arow * kH + koff;
            short8 a[16];
            LLC_LOAD16(a, hp2);
#pragma unroll
            for (int kk = 0; kk < 16; ++kk) {
#pragma unroll
                for (int gg = 0; gg < 4; ++gg) {
                    short8 b = *(const short8*)&lw[((64 + gg * 16 + kk) << 9) + (lane << 3)];
                    acc[gg] = __builtin_amdgcn_mfma_f32_16x16x32_bf16(a[kk], b, acc[gg], 0, 0, 0);
                }
            }

            if (wave == 0) waitf(f1, u + 1, lane, fc1); // L1 done step u
            __syncthreads();

            const unsigned short* hp1 = h1r + ((size_t)(u & 3)) * kHSlot
                                        + (size_t)arow * kH + koff;   // h1[u]
            LLC_LOAD16(a, hp1);
#pragma unroll
            for (int kk = 0; kk < 16; ++kk) {
#pragma unroll
                for (int gg = 0; gg < 4; ++gg) {
                    short8 b = *(const short8*)&lw[((gg * 16 + kk) << 9) + (lane << 3)];
                    acc[gg] = __builtin_amdgcn_mfma_f32_16x16x32_bf16(a[kk], b, acc[gg], 0, 0, 0);
                }
            }

            unsigned short* hw = h2r + ((size_t)(u & 1)) * kHSlot;
            const int j = j0 + lcol;
#pragma unroll
            for (int r = 0; r < 4; ++r) {
                int row = quad * 4 + r;
                float gi = acc[0][r], gf = acc[1][r], ggv = acc[2][r], go = acc[3][r];
                float cn = sigm(gf) * creg[r] + sigm(gi) * tanh_(ggv);
                float hn = sigm(go) * tanh_(cn);
                creg[r] = cn;
                scr[row * 24 + lcol] = f2bf(hn);
                if (u == kSeq - 1) h2f[(size_t)(m0 + row) * kH + j] = hn;
            }
            __syncthreads();
            if (lane < 32) {
                int row = lane >> 1, seg = lane & 1;
                short8 v = *(short8*)&scr[row * 24 + seg * 8];
                unsigned short* gp = hw + (size_t)(m0 + row) * kH + j0 + seg * 8;
                LLC_STORE16(gp, v);
            }
            __builtin_amdgcn_s_waitcnt(0);
            __syncthreads();
            if (tid == 0)
                __hip_atomic_store(myflag, u + 1,
                                   __ATOMIC_RELAXED, __HIP_MEMORY_SCOPE_AGENT);
        }
    }
}

__global__ __launch_bounds__(64) void k_head(
    const float* __restrict__ h2f, const float* __restrict__ fc1w,
    const float* __restrict__ fc1b, const float* __restrict__ fcw,
    const float* __restrict__ fcb, float* __restrict__ out)
{
    int m = blockIdx.x;
    int j = threadIdx.x;
    const float* hr = h2f + (size_t)m * kH;
    const float* wr = fc1w + (size_t)j * kH;
    float sacc = 0.f;
    for (int k = 0; k < kH; ++k) sacc += fmaxf(hr[k], 0.f) * wr[k];
    float rv = fmaxf(sacc + fc1b[j], 0.f) * fcw[j];
#pragma unroll
    for (int off = 32; off >= 1; off >>= 1) rv += __shfl_down(rv, off);
    if (j == 0) out[m] = 2.0f * (rv + fcb[0]);
}

extern "C" void kernel_launch(void* const* d_in, const int* in_sizes, int n_in,
                              void* d_out, int out_size, void* d_ws, size_t ws_size,
                              hipStream_t stream) {
    const float* x    = (const float*)d_in[0];
    const float* Wih1 = (const float*)d_in[1];
    const float* Whh1 = (const float*)d_in[2];
    const float* bih1 = (const float*)d_in[3];
    const float* bhh1 = (const float*)d_in[4];
    const float* Wih2 = (const float*)d_in[5];
    const float* Whh2 = (const float*)d_in[6];
    const float* bih2 = (const float*)d_in[7];
    const float* bhh2 = (const float*)d_in[8];
    const float* fc1w = (const float*)d_in[9];
    const float* fc1b = (const float*)d_in[10];
    const float* fcw  = (const float*)d_in[11];
    const float* fcb  = (const float*)d_in[12];
    float* out = (float*)d_out;

    char* p = (char*)d_ws;
    auto take = [&](size_t bytes) -> char* {
        char* r = p;
        p += (bytes + 255) & ~(size_t)255;
        return r;
    };
    unsigned short* whh1b = (unsigned short*)take((size_t)kG * kH * 2);
    unsigned short* wih2b = (unsigned short*)take((size_t)kG * kH * 2);
    unsigned short* whh2b = (unsigned short*)take((size_t)kG * kH * 2);
    unsigned short* wih1b = (unsigned short*)take((size_t)kG * 32 * 2);
    unsigned short* xb    = (unsigned short*)take((size_t)kSeq * kBatch * 32 * 2);
    char* state = p;
    unsigned short* h1r = (unsigned short*)take(4 * kHSlot * 2);
    unsigned short* h2r = (unsigned short*)take(2 * kHSlot * 2);
    int* flags = (int*)take(16384);
    size_t state_bytes = (size_t)((char*)flags + 16384 - state);
    float* h2f = (float*)take((size_t)kBatch * kH * 4);

    hipMemsetAsync(state, 0, state_bytes, stream);

    int n = kG * kH;
    k_conv<<<(n + 255) / 256, 256, 0, stream>>>(Whh1, whh1b, n);
    k_conv<<<(n + 255) / 256, 256, 0, stream>>>(Wih2, wih2b, n);
    k_conv<<<(n + 255) / 256, 256, 0, stream>>>(Whh2, whh2b, n);
    k_conv_pad<<<(kG * 32 + 255) / 256, 256, 0, stream>>>(Wih1, wih1b, kG);
    k_conv_pad<<<(kSeq * kBatch * 32 + 255) / 256, 256, 0, stream>>>(x, xb, kSeq * kBatch);

    hipFuncSetAttribute((const void*)k_persist,
                        hipFuncAttributeMaxDynamicSharedMemorySize, (int)kShmemBytes);
    void* args[] = {&whh1b, &wih1b, &wih2b, &whh2b, &xb,
                    (void*)&bih1, (void*)&bhh1, (void*)&bih2, (void*)&bhh2,
                    &h1r, &h2r, &h2f, &flags};
    hipError_t e = hipLaunchCooperativeKernel((const void*)k_persist, dim3(256), dim3(256),
                                              args, (unsigned)kShmemBytes, stream);
    if (e != hipSuccess) {
        k_persist<<<256, 256, kShmemBytes, stream>>>(
            whh1b, wih1b, wih2b, whh2b, xb, bih1, bhh1, bih2, bhh2,
            h1r, h2r, h2f, flags);
    }

    k_head<<<kBatch, 64, 0, stream>>>(h2f, fc1w, fc1b, fcw, fcb, out);
}

// Round 8
// 4190.182 us; speedup vs baseline: 1.9809x; 1.0162x over previous
//
#include <hip/hip_runtime.h>
#include <cstdint>
#include <cstddef>

typedef __attribute__((ext_vector_type(8))) short short8;
typedef __attribute__((ext_vector_type(4))) float floatx4;

constexpr int kSeq = 512;
constexpr int kBatch = 256;
constexpr int kIn = 15;
constexpr int kH = 512;
constexpr int kG = 4 * kH;                      // 2048 gate cols, order i,f,g,o
constexpr int kRing = 17;                       // ring depth (> window 16, coprime)
constexpr size_t kHSlot = (size_t)kBatch * kH;  // elements per h slot
// LDS: 128 KB weights (fragment-linear) + 4 waves * 768 B transpose scratch
constexpr size_t kShmemBytes = 131072 + 4096;

__device__ __forceinline__ unsigned short f2bf(float f) {
    union { float f; unsigned u; } v; v.f = f;
    unsigned u = v.u;
    return (unsigned short)((u + 0x7fffu + ((u >> 16) & 1u)) >> 16);
}

__device__ __forceinline__ float sigm(float x) { return 1.0f / (1.0f + __expf(-x)); }
__device__ __forceinline__ float tanh_(float x) { return 1.0f - 2.0f / (1.0f + __expf(2.0f * x)); }

// 16-B write-through store (LLC always current; h never dirty in any L2)
#define LLC_STORE16(P, V)                                                     \
    asm volatile("global_store_dwordx4 %0, %1, off sc0 sc1"                   \
                 :: "v"(P), "v"(V) : "memory")

// Wave-0 poll: lanes 0..31 each watch one flag (64 B apart). Register cache fc
// exploits monotonicity — a satisfied wait does zero memory ops.
__device__ __forceinline__ void waitf(const int* flags, int tgt, int lane, int& fc) {
    if (tgt <= 0) return;
    bool watch = (lane < 32);
    if (__all(!watch || fc >= tgt)) return;
    for (;;) {
        if (watch && fc < tgt)
            fc = __hip_atomic_load(flags + lane * 16,
                                   __ATOMIC_RELAXED, __HIP_MEMORY_SCOPE_AGENT);
        if (__all(!watch || fc >= tgt)) return;
        __builtin_amdgcn_s_sleep(1);
    }
}

__global__ void k_conv(const float* __restrict__ src, unsigned short* __restrict__ dst, int n) {
    int i = blockIdx.x * blockDim.x + threadIdx.x;
    if (i < n) dst[i] = f2bf(src[i]);
}

__global__ void k_conv_pad(const float* __restrict__ src, unsigned short* __restrict__ dst, int rows) {
    int i = blockIdx.x * blockDim.x + threadIdx.x;
    if (i >= rows * 32) return;
    int r = i >> 5, k = i & 31;
    dst[i] = (k < kIn) ? f2bf(src[r * kIn + k]) : (unsigned short)0;
}

// Persistent kernel. group g = blockIdx&3 (64 batch rows, 2-XCD-affine under RR
// dispatch); role = blockIdx>>2: 0..31 layer-1, 32..63 layer-2 (16 units each).
// h1/h2: 17-slot rings. Producers: sc0sc1 write-through. Consumers: PLAIN
// CACHED loads (redundancy absorbed by per-XCD L2/L1), made safe by a
// group rendezvous + agent acquire fence every 16 steps:
//   - rendezvous at boundary B waits f1>=B && f2>=B  => all reads for steps <B
//     are complete before any fence;
//   - any two reads of the same ring address are >=16 steps apart (ring 17),
//     so each reader fences between old-value and new-value reads.
__global__ __launch_bounds__(256) void k_persist(
    const unsigned short* __restrict__ whh1b,
    const unsigned short* __restrict__ wih1b,
    const unsigned short* __restrict__ wih2b,
    const unsigned short* __restrict__ whh2b,
    const unsigned short* __restrict__ xb,
    const float* __restrict__ bih1, const float* __restrict__ bhh1,
    const float* __restrict__ bih2, const float* __restrict__ bhh2,
    unsigned short* __restrict__ h1r,   // kRing slots of kBatch*kH
    unsigned short* __restrict__ h2r,   // kRing slots of kBatch*kH
    float* __restrict__ h2f,
    int* __restrict__ flags)            // per group: f1[32] @ +0, f2[32] @ +512 ints
{
    extern __shared__ unsigned short lw[];
    const int bid = blockIdx.x;
    const int g = bid & 3;
    const int role = bid >> 2;
    const bool is2 = role >= 32;
    const int rid = role & 31;
    const int j0 = rid << 4;
    const int tid = (int)threadIdx.x;
    const int wave = tid >> 6;
    const int lane = tid & 63;
    const int lcol = lane & 15;
    const int quad = lane >> 4;
    const int m0 = (g << 6) + wave * 16;
    const int arow = m0 + lcol;
    const int koff = quad * 8;

    int* f1 = flags + g * 1024;
    int* f2 = f1 + 512;
    int* myflag = (is2 ? f2 : f1) + rid * 16;
    unsigned short* scr = lw + 65536 + wave * 384;   // 16 rows x stride-24 elems

    // ---- stage weight slices into LDS, fragment-linear layout ----
    if (!is2) {
        for (int i = tid; i < 4096; i += 256) {
            int ln = i >> 6, gg = ln >> 4, u = ln & 15;
            int c = i & 63, kk = c >> 2, qd = c & 3;
            *(short8*)&lw[((gg * 16 + kk) << 9) + ((qd * 16 + u) << 3)] =
                *(const short8*)&whh1b[(size_t)((gg << 9) + j0 + u) * kH + c * 8];
        }
        for (int i = tid; i < 256; i += 256) {
            int ln = i >> 2, gg = ln >> 4, u = ln & 15;
            int qd = i & 3;
            *(short8*)&lw[((64 + gg) << 9) + ((qd * 16 + u) << 3)] =
                *(const short8*)&wih1b[((gg << 9) + j0 + u) * 32 + qd * 8];
        }
    } else {
        for (int i = tid; i < 4096; i += 256) {
            int ln = i >> 6, gg = ln >> 4, u = ln & 15;
            int c = i & 63, kk = c >> 2, qd = c & 3;
            int dst = ((gg * 16 + kk) << 9) + ((qd * 16 + u) << 3);
            size_t src = (size_t)((gg << 9) + j0 + u) * kH + c * 8;
            *(short8*)&lw[dst] = *(const short8*)&wih2b[src];
            *(short8*)&lw[dst + (64 << 9)] = *(const short8*)&whh2b[src];
        }
    }
    float bsum[4];
#pragma unroll
    for (int gg = 0; gg < 4; ++gg) {
        int n = (gg << 9) + j0 + lcol;
        bsum[gg] = is2 ? (bih2[n] + bhh2[n]) : (bih1[n] + bhh1[n]);
    }
    __syncthreads();

    float creg[4] = {0.f, 0.f, 0.f, 0.f};
    int fc1 = 0, fc2 = 0;   // wave-0 flag caches

    if (!is2) {
        for (int s = 0; s < kSeq; ++s) {
            if ((s & 15) == 0) {      // window rendezvous + cache invalidate
                if (wave == 0) { waitf(f1, s, lane, fc1); waitf(f2, s, lane, fc2); }
                __syncthreads();
                __builtin_amdgcn_fence(__ATOMIC_ACQUIRE, "agent");
            }
            floatx4 acc[4];
#pragma unroll
            for (int gg = 0; gg < 4; ++gg)
                acc[gg] = (floatx4){bsum[gg], bsum[gg], bsum[gg], bsum[gg]};

            short8 ax = *(const short8*)(xb + ((size_t)s * kBatch + arow) * 32 + koff);

            if (wave == 0) waitf(f1, s, lane, fc1);     // peers done s-1
            __syncthreads();

            const unsigned short* hp = h1r + (size_t)((s + 16) % kRing) * kHSlot
                                       + (size_t)arow * kH + koff;   // h1[s-1]
            short8 a[16];
#pragma unroll
            for (int kk = 0; kk < 16; ++kk) a[kk] = *(const short8*)(hp + kk * 32);
#pragma unroll
            for (int kk = 0; kk < 16; ++kk) {
#pragma unroll
                for (int gg = 0; gg < 4; ++gg) {
                    short8 b = *(const short8*)&lw[((gg * 16 + kk) << 9) + (lane << 3)];
                    acc[gg] = __builtin_amdgcn_mfma_f32_16x16x32_bf16(a[kk], b, acc[gg], 0, 0, 0);
                }
            }
#pragma unroll
            for (int gg = 0; gg < 4; ++gg) {
                short8 b = *(const short8*)&lw[((64 + gg) << 9) + (lane << 3)];
                acc[gg] = __builtin_amdgcn_mfma_f32_16x16x32_bf16(ax, b, acc[gg], 0, 0, 0);
            }

            // epilogue: activations -> per-wave LDS transpose -> 16B WT stores
            unsigned short* hw = h1r + (size_t)(s % kRing) * kHSlot;
#pragma unroll
            for (int r = 0; r < 4; ++r) {
                int row = quad * 4 + r;
                float gi = acc[0][r], gf = acc[1][r], ggv = acc[2][r], go = acc[3][r];
                float cn = sigm(gf) * creg[r] + sigm(gi) * tanh_(ggv);
                float hn = sigm(go) * tanh_(cn);
                creg[r] = cn;
                scr[row * 24 + lcol] = f2bf(hn);
            }
            __syncthreads();
            if (lane < 32) {
                int row = lane >> 1, seg = lane & 1;
                short8 v = *(short8*)&scr[row * 24 + seg * 8];
                unsigned short* gp = hw + (size_t)(m0 + row) * kH + j0 + seg * 8;
                LLC_STORE16(gp, v);
            }
            __builtin_amdgcn_s_waitcnt(0);
            __syncthreads();
            if (tid == 0)
                __hip_atomic_store(myflag, s + 1,
                                   __ATOMIC_RELAXED, __HIP_MEMORY_SCOPE_AGENT);
        }
    } else {
        for (int u = 0; u < kSeq; ++u) {
            if ((u & 15) == 0) {      // window rendezvous + cache invalidate
                if (wave == 0) { waitf(f1, u, lane, fc1); waitf(f2, u, lane, fc2); }
                __syncthreads();
                __builtin_amdgcn_fence(__ATOMIC_ACQUIRE, "agent");
            }
            floatx4 acc[4];
#pragma unroll
            for (int gg = 0; gg < 4; ++gg)
                acc[gg] = (floatx4){bsum[gg], bsum[gg], bsum[gg], bsum[gg]};

            if (wave == 0) waitf(f2, u, lane, fc2);     // peers done u-1
            __syncthreads();

            // h2[u-1] GEMM first (hides under L1's tail)
            const unsigned short* hp2 = h2r + (size_t)((u + 16) % kRing) * kHSlot
                                        + (size_t)arow * kH + koff;
            short8 a[16];
#pragma unroll
            for (int kk = 0; kk < 16; ++kk) a[kk] = *(const short8*)(hp2 + kk * 32);
#pragma unroll
            for (int kk = 0; kk < 16; ++kk) {
#pragma unroll
                for (int gg = 0; gg < 4; ++gg) {
                    short8 b = *(const short8*)&lw[((64 + gg * 16 + kk) << 9) + (lane << 3)];
                    acc[gg] = __builtin_amdgcn_mfma_f32_16x16x32_bf16(a[kk], b, acc[gg], 0, 0, 0);
                }
            }

            if (wave == 0) waitf(f1, u + 1, lane, fc1); // L1 done step u
            __syncthreads();

            const unsigned short* hp1 = h1r + (size_t)(u % kRing) * kHSlot
                                        + (size_t)arow * kH + koff;   // h1[u]
#pragma unroll
            for (int kk = 0; kk < 16; ++kk) a[kk] = *(const short8*)(hp1 + kk * 32);
#pragma unroll
            for (int kk = 0; kk < 16; ++kk) {
#pragma unroll
                for (int gg = 0; gg < 4; ++gg) {
                    short8 b = *(const short8*)&lw[((gg * 16 + kk) << 9) + (lane << 3)];
                    acc[gg] = __builtin_amdgcn_mfma_f32_16x16x32_bf16(a[kk], b, acc[gg], 0, 0, 0);
                }
            }

            unsigned short* hw = h2r + (size_t)(u % kRing) * kHSlot;
            const int j = j0 + lcol;
#pragma unroll
            for (int r = 0; r < 4; ++r) {
                int row = quad * 4 + r;
                float gi = acc[0][r], gf = acc[1][r], ggv = acc[2][r], go = acc[3][r];
                float cn = sigm(gf) * creg[r] + sigm(gi) * tanh_(ggv);
                float hn = sigm(go) * tanh_(cn);
                creg[r] = cn;
                scr[row * 24 + lcol] = f2bf(hn);
                if (u == kSeq - 1) h2f[(size_t)(m0 + row) * kH + j] = hn;
            }
            __syncthreads();
            if (lane < 32) {
                int row = lane >> 1, seg = lane & 1;
                short8 v = *(short8*)&scr[row * 24 + seg * 8];
                unsigned short* gp = hw + (size_t)(m0 + row) * kH + j0 + seg * 8;
                LLC_STORE16(gp, v);
            }
            __builtin_amdgcn_s_waitcnt(0);
            __syncthreads();
            if (tid == 0)
                __hip_atomic_store(myflag, u + 1,
                                   __ATOMIC_RELAXED, __HIP_MEMORY_SCOPE_AGENT);
        }
    }
}

__global__ __launch_bounds__(64) void k_head(
    const float* __restrict__ h2f, const float* __restrict__ fc1w,
    const float* __restrict__ fc1b, const float* __restrict__ fcw,
    const float* __restrict__ fcb, float* __restrict__ out)
{
    int m = blockIdx.x;
    int j = threadIdx.x;
    const float* hr = h2f + (size_t)m * kH;
    const float* wr = fc1w + (size_t)j * kH;
    float sacc = 0.f;
    for (int k = 0; k < kH; ++k) sacc += fmaxf(hr[k], 0.f) * wr[k];
    float rv = fmaxf(sacc + fc1b[j], 0.f) * fcw[j];
#pragma unroll
    for (int off = 32; off >= 1; off >>= 1) rv += __shfl_down(rv, off);
    if (j == 0) out[m] = 2.0f * (rv + fcb[0]);
}

extern "C" void kernel_launch(void* const* d_in, const int* in_sizes, int n_in,
                              void* d_out, int out_size, void* d_ws, size_t ws_size,
                              hipStream_t stream) {
    const float* x    = (const float*)d_in[0];
    const float* Wih1 = (const float*)d_in[1];
    const float* Whh1 = (const float*)d_in[2];
    const float* bih1 = (const float*)d_in[3];
    const float* bhh1 = (const float*)d_in[4];
    const float* Wih2 = (const float*)d_in[5];
    const float* Whh2 = (const float*)d_in[6];
    const float* bih2 = (const float*)d_in[7];
    const float* bhh2 = (const float*)d_in[8];
    const float* fc1w = (const float*)d_in[9];
    const float* fc1b = (const float*)d_in[10];
    const float* fcw  = (const float*)d_in[11];
    const float* fcb  = (const float*)d_in[12];
    float* out = (float*)d_out;

    char* p = (char*)d_ws;
    auto take = [&](size_t bytes) -> char* {
        char* r = p;
        p += (bytes + 255) & ~(size_t)255;
        return r;
    };
    unsigned short* whh1b = (unsigned short*)take((size_t)kG * kH * 2);
    unsigned short* wih2b = (unsigned short*)take((size_t)kG * kH * 2);
    unsigned short* whh2b = (unsigned short*)take((size_t)kG * kH * 2);
    unsigned short* wih1b = (unsigned short*)take((size_t)kG * 32 * 2);
    unsigned short* xb    = (unsigned short*)take((size_t)kSeq * kBatch * 32 * 2);
    char* state = p;
    unsigned short* h1r = (unsigned short*)take((size_t)kRing * kHSlot * 2);
    unsigned short* h2r = (unsigned short*)take((size_t)kRing * kHSlot * 2);
    int* flags = (int*)take(16384);
    size_t state_bytes = (size_t)((char*)flags + 16384 - state);
    float* h2f = (float*)take((size_t)kBatch * kH * 4);

    hipMemsetAsync(state, 0, state_bytes, stream);

    int n = kG * kH;
    k_conv<<<(n + 255) / 256, 256, 0, stream>>>(Whh1, whh1b, n);
    k_conv<<<(n + 255) / 256, 256, 0, stream>>>(Wih2, wih2b, n);
    k_conv<<<(n + 255) / 256, 256, 0, stream>>>(Whh2, whh2b, n);
    k_conv_pad<<<(kG * 32 + 255) / 256, 256, 0, stream>>>(Wih1, wih1b, kG);
    k_conv_pad<<<(kSeq * kBatch * 32 + 255) / 256, 256, 0, stream>>>(x, xb, kSeq * kBatch);

    hipFuncSetAttribute((const void*)k_persist,
                        hipFuncAttributeMaxDynamicSharedMemorySize, (int)kShmemBytes);
    void* args[] = {&whh1b, &wih1b, &wih2b, &whh2b, &xb,
                    (void*)&bih1, (void*)&bhh1, (void*)&bih2, (void*)&bhh2,
                    &h1r, &h2r, &h2f, &flags};
    hipError_t e = hipLaunchCooperativeKernel((const void*)k_persist, dim3(256), dim3(256),
                                              args, (unsigned)kShmemBytes, stream);
    if (e != hipSuccess) {
        k_persist<<<256, 256, kShmemBytes, stream>>>(
            whh1b, wih1b, wih2b, whh2b, xb, bih1, bhh1, bih2, bhh2,
            h1r, h2r, h2f, flags);
    }

    k_head<<<kBatch, 64, 0, stream>>>(h2f, fc1w, fc1b, fcw, fcb, out);
}